// Round 1
// baseline (20828.186 us; speedup 1.0000x reference)
//
#include <hip/hip_runtime.h>

#define TPB 256
constexpr int LS = 264600;          // 6.0 s * 44100 Hz
constexpr int N1 = 525;             // LS = N1 * N2
constexpr int N2 = 504;
constexpr int ROWS = 32;            // S*C = 16*2
constexpr float TWO_PI_F = 6.28318530717958647692f;

// ---------------------------------------------------------------------------
// K0: per-bin scan of G for the nonzero head/tail block sizes.
// G rows are: [0,h) nonzero, [h, NL-nh) exact 0.0f padding, [NL-nh, NL) nonzero.
// The Hann midpoint (first tail element) may itself be exactly 0.0 — excluding
// it is harmless since its weight is 0.
// ---------------------------------------------------------------------------
__global__ void k0_scan(const float* __restrict__ G, int NL, int* __restrict__ hnh) {
    const int j = blockIdx.x;
    __shared__ int s_first, s_last;
    if (threadIdx.x == 0) { s_first = NL; s_last = -1; }
    __syncthreads();
    const float* Gj = G + (size_t)j * NL;
    for (int m = threadIdx.x; m < NL; m += blockDim.x) {
        if (Gj[m] == 0.0f) {
            atomicMin(&s_first, m);
            atomicMax(&s_last, m);
        }
    }
    __syncthreads();
    if (threadIdx.x == 0) {
        int h  = s_first;                                  // NL if no zeros
        int nh = (s_last >= 0) ? (NL - 1 - s_last) : 0;
        hnh[2 * j]     = h;
        hnh[2 * j + 1] = nh;
    }
}

// ---------------------------------------------------------------------------
// K1: stage 1 of forward FFT. For each (row r, n2): 525-point DFT over
// x[r, n2 + 504*n1], then multiply by inter-stage twiddle W_LS^{n2*k1}.
// Writes A[r][k1][n2].
// ---------------------------------------------------------------------------
__global__ __launch_bounds__(TPB) void k1_dft525(const float* __restrict__ x,
                                                 float2* __restrict__ A) {
    const int n2 = blockIdx.x;   // [0, 504)
    const int r  = blockIdx.y;   // [0, 32)
    __shared__ float  xs[N1];
    __shared__ float2 tw[N1];
    const float* xr = x + (size_t)r * LS + n2;
    for (int t = threadIdx.x; t < N1; t += TPB) {
        xs[t] = xr[(size_t)t * N2];
        float a = -TWO_PI_F * (float)t / (float)N1;
        float s, c; sincosf(a, &s, &c);
        tw[t] = make_float2(c, s);
    }
    __syncthreads();
    for (int k1 = threadIdx.x; k1 < N1; k1 += TPB) {
        float re = 0.f, im = 0.f;
        int tt = 0;
        #pragma unroll 5
        for (int n1 = 0; n1 < N1; ++n1) {
            float  xv = xs[n1];
            float2 w  = tw[tt];
            re = fmaf(xv, w.x, re);
            im = fmaf(xv, w.y, im);
            tt += k1; if (tt >= N1) tt -= N1;
        }
        // inter-stage twiddle W_LS^{k1*n2}
        float ang = -TWO_PI_F * (float)(k1 * n2) / (float)LS;
        float s, c; sincosf(ang, &s, &c);
        float ore = re * c - im * s;
        float oim = re * s + im * c;
        A[((size_t)r * N1 + k1) * N2 + n2] = make_float2(ore, oim);
    }
}

// ---------------------------------------------------------------------------
// K2: stage 2. For each (row r, k1): in-place 504-point DFT over n2.
// After this, ft[r][k] lives at A[r][k % 525][k / 525].
// ---------------------------------------------------------------------------
__global__ __launch_bounds__(TPB) void k2_dft504(float2* __restrict__ A) {
    const int k1 = blockIdx.x;   // [0, 525)
    const int r  = blockIdx.y;
    __shared__ float2 as[N2];
    __shared__ float2 tw[N2];
    float2* row = A + ((size_t)r * N1 + k1) * N2;
    for (int t = threadIdx.x; t < N2; t += TPB) {
        as[t] = row[t];
        float a = -TWO_PI_F * (float)t / (float)N2;
        float s, c; sincosf(a, &s, &c);
        tw[t] = make_float2(c, s);
    }
    __syncthreads();
    for (int k2 = threadIdx.x; k2 < N2; k2 += TPB) {
        float re = 0.f, im = 0.f;
        int tt = 0;
        #pragma unroll 4
        for (int t = 0; t < N2; ++t) {
            float2 a = as[t];
            float2 w = tw[tt];
            re = fmaf(a.x, w.x, re); re = fmaf(-a.y, w.y, re);
            im = fmaf(a.x, w.y, im); im = fmaf( a.y, w.x, im);
            tt += k2; if (tt >= N2) tt -= N2;
        }
        row[k2] = make_float2(re, im);   // safe: all reads come from LDS
    }
}

// ---------------------------------------------------------------------------
// K3: per (row, bin): gather c[m] = G[j,m]*ft[r, idx[j,m]] for the nonzero m
// (head block [0,h), tail block [NL-nh, NL)) into LDS, then direct sparse
// IDFT: y[n] = (100/NL) * sum_m c[m] * e^{+2*pi*i*m*n/NL}, for n in [0, NL).
// Twiddle via complex recurrence, exact sincosf refresh every 256 terms.
// ---------------------------------------------------------------------------
__global__ __launch_bounds__(TPB) void k3_idft(const float* __restrict__ G,
                                               const int*  __restrict__ idxp,
                                               const float2* __restrict__ FT,
                                               const int*  __restrict__ hnh,
                                               float2* __restrict__ out,
                                               int NB, int NL) {
    extern __shared__ float2 cls[];   // NL entries max
    const int j = blockIdx.x;
    const int r = blockIdx.y;
    const int h  = hnh[2 * j];
    const int nh = hnh[2 * j + 1];
    const int Lg = h + nh;
    const float* Gj = G    + (size_t)j * NL;
    const int*   ij = idxp + (size_t)j * NL;

    for (int t = threadIdx.x; t < Lg; t += TPB) {
        int m = (t < h) ? t : (NL - nh + (t - h));
        int k = ij[m];
        int k1 = k % N1;
        int k2 = k / N1;
        float2 f = FT[((size_t)r * N1 + k1) * N2 + k2];
        float  g = Gj[m];
        cls[t] = make_float2(f.x * g, f.y * g);
    }
    __syncthreads();

    const float scale = 100.0f / (float)NL;
    const float w0 = TWO_PI_F / (float)NL;
    float2* outr = out + ((size_t)r * NB + j) * NL;

    for (int n_base = 0; n_base < NL; n_base += 4 * TPB) {
        int   n[4];
        float are[4], aim[4], twr[4], twi[4], str[4], sti[4];
        #pragma unroll
        for (int u = 0; u < 4; ++u) {
            n[u] = n_base + u * TPB + (int)threadIdx.x;
            are[u] = 0.f; aim[u] = 0.f;
            float s, c; sincosf(w0 * (float)(n[u] % NL), &s, &c);
            str[u] = c; sti[u] = s;      // step = e^{+2pi i n / NL}
            twr[u] = 1.f; twi[u] = 0.f;
        }
        // segment 1: m = t in [0, h)
        for (int t = 0; t < h; ++t) {
            if ((t & 255) == 0) {
                #pragma unroll
                for (int u = 0; u < 4; ++u) {
                    int mm = (int)(((long long)t * (long long)n[u]) % NL);
                    float s, c; sincosf(w0 * (float)mm, &s, &c);
                    twr[u] = c; twi[u] = s;
                }
            }
            float2 cv = cls[t];
            #pragma unroll
            for (int u = 0; u < 4; ++u) {
                are[u] = fmaf(cv.x, twr[u], are[u]);
                are[u] = fmaf(-cv.y, twi[u], are[u]);
                aim[u] = fmaf(cv.x, twi[u], aim[u]);
                aim[u] = fmaf(cv.y, twr[u], aim[u]);
                float nr = twr[u] * str[u] - twi[u] * sti[u];
                float ni = twr[u] * sti[u] + twi[u] * str[u];
                twr[u] = nr; twi[u] = ni;
            }
        }
        // segment 2: m = NL - nh + t, t in [0, nh)
        const int m0 = NL - nh;
        for (int t = 0; t < nh; ++t) {
            if ((t & 255) == 0) {
                #pragma unroll
                for (int u = 0; u < 4; ++u) {
                    int mm = (int)(((long long)(m0 + t) * (long long)n[u]) % NL);
                    float s, c; sincosf(w0 * (float)mm, &s, &c);
                    twr[u] = c; twi[u] = s;
                }
            }
            float2 cv = cls[h + t];
            #pragma unroll
            for (int u = 0; u < 4; ++u) {
                are[u] = fmaf(cv.x, twr[u], are[u]);
                are[u] = fmaf(-cv.y, twi[u], are[u]);
                aim[u] = fmaf(cv.x, twi[u], aim[u]);
                aim[u] = fmaf(cv.y, twr[u], aim[u]);
                float nr = twr[u] * str[u] - twi[u] * sti[u];
                float ni = twr[u] * sti[u] + twi[u] * str[u];
                twr[u] = nr; twi[u] = ni;
            }
        }
        #pragma unroll
        for (int u = 0; u < 4; ++u) {
            if (n[u] < NL) {
                outr[n[u]] = make_float2(are[u] * scale, aim[u] * scale);
            }
        }
    }
}

// ---------------------------------------------------------------------------
extern "C" void kernel_launch(void* const* d_in, const int* in_sizes, int n_in,
                              void* d_out, int out_size, void* d_ws, size_t ws_size,
                              hipStream_t stream) {
    const float* x   = (const float*)d_in[0];
    const float* G   = (const float*)d_in[1];
    const int*   idx = (const int*)d_in[2];
    float2*      out = (float2*)d_out;

    const int p  = in_sizes[1];                 // n_bins * maxLg
    const int NB = (p % 114 == 0) ? 114 : 115;  // mel round-trip knife edge
    const int NL = p / NB;

    int*    hnh = (int*)d_ws;
    float2* A   = (float2*)((char*)d_ws + 1024);  // 32*264600 complex = 67.7 MB

    k0_scan<<<dim3(NB), TPB, 0, stream>>>(G, NL, hnh);
    k1_dft525<<<dim3(N2, ROWS), TPB, 0, stream>>>(x, A);
    k2_dft504<<<dim3(N1, ROWS), TPB, 0, stream>>>(A);
    k3_idft<<<dim3(NB, ROWS), TPB, (size_t)NL * sizeof(float2), stream>>>(
        G, idx, A, hnh, out, NB, NL);
}

// Round 2
// 3434.608 us; speedup vs baseline: 6.0642x; 6.0642x over previous
//
#include <hip/hip_runtime.h>

#define TPB 256
constexpr int LS = 264600;          // 6.0 s * 44100 Hz
constexpr int N1 = 525;             // LS = N1 * N2
constexpr int N2 = 504;
constexpr int ROWS = 32;            // S*C = 16*2
constexpr int M_FFT = 16384;        // Bluestein conv length >= 2*NL-1 (NL<=8192)
constexpr float TWO_PI_F = 6.28318530717958647692f;
constexpr float PI_F     = 3.14159265358979323846f;

__device__ __forceinline__ int rev7(int x) { return (int)(__brev((unsigned)x) >> 25); }
__device__ __forceinline__ float2 cmul(float2 a, float2 b) {
    return make_float2(a.x * b.x - a.y * b.y, a.x * b.y + a.y * b.x);
}

// ---------------------------------------------------------------------------
// K0: per-bin scan of G for nonzero head/tail block sizes (exact-0 padding).
// ---------------------------------------------------------------------------
__global__ void k0_scan(const float* __restrict__ G, int NL, int* __restrict__ hnh) {
    const int j = blockIdx.x;
    __shared__ int s_first, s_last;
    if (threadIdx.x == 0) { s_first = NL; s_last = -1; }
    __syncthreads();
    const float* Gj = G + (size_t)j * NL;
    for (int m = threadIdx.x; m < NL; m += blockDim.x) {
        if (Gj[m] == 0.0f) {
            atomicMin(&s_first, m);
            atomicMax(&s_last, m);
        }
    }
    __syncthreads();
    if (threadIdx.x == 0) {
        int h  = s_first;
        int nh = (s_last >= 0) ? (NL - 1 - s_last) : 0;
        hnh[2 * j]     = h;
        hnh[2 * j + 1] = nh;
    }
}

// ---------------------------------------------------------------------------
// K1/K2: forward FFT of x, four-step 525 x 504 (unchanged from round 1).
// ---------------------------------------------------------------------------
__global__ __launch_bounds__(TPB) void k1_dft525(const float* __restrict__ x,
                                                 float2* __restrict__ A) {
    const int n2 = blockIdx.x;
    const int r  = blockIdx.y;
    __shared__ float  xs[N1];
    __shared__ float2 tw[N1];
    const float* xr = x + (size_t)r * LS + n2;
    for (int t = threadIdx.x; t < N1; t += TPB) {
        xs[t] = xr[(size_t)t * N2];
        float a = -TWO_PI_F * (float)t / (float)N1;
        float s, c; sincosf(a, &s, &c);
        tw[t] = make_float2(c, s);
    }
    __syncthreads();
    for (int k1 = threadIdx.x; k1 < N1; k1 += TPB) {
        float re = 0.f, im = 0.f;
        int tt = 0;
        #pragma unroll 5
        for (int n1 = 0; n1 < N1; ++n1) {
            float  xv = xs[n1];
            float2 w  = tw[tt];
            re = fmaf(xv, w.x, re);
            im = fmaf(xv, w.y, im);
            tt += k1; if (tt >= N1) tt -= N1;
        }
        float ang = -TWO_PI_F * (float)(k1 * n2) / (float)LS;
        float s, c; sincosf(ang, &s, &c);
        A[((size_t)r * N1 + k1) * N2 + n2] = make_float2(re * c - im * s, re * s + im * c);
    }
}

__global__ __launch_bounds__(TPB) void k2_dft504(float2* __restrict__ A) {
    const int k1 = blockIdx.x;
    const int r  = blockIdx.y;
    __shared__ float2 as[N2];
    __shared__ float2 tw[N2];
    float2* row = A + ((size_t)r * N1 + k1) * N2;
    for (int t = threadIdx.x; t < N2; t += TPB) {
        as[t] = row[t];
        float a = -TWO_PI_F * (float)t / (float)N2;
        float s, c; sincosf(a, &s, &c);
        tw[t] = make_float2(c, s);
    }
    __syncthreads();
    for (int k2 = threadIdx.x; k2 < N2; k2 += TPB) {
        float re = 0.f, im = 0.f;
        int tt = 0;
        #pragma unroll 4
        for (int t = 0; t < N2; ++t) {
            float2 a = as[t];
            float2 w = tw[tt];
            re = fmaf(a.x, w.x, re); re = fmaf(-a.y, w.y, re);
            im = fmaf(a.x, w.y, im); im = fmaf( a.y, w.x, im);
            tt += k2; if (tt >= N2) tt -= N2;
        }
        row[k2] = make_float2(re, im);
    }
}

// ---------------------------------------------------------------------------
// K_SETUP: chirp tables. bchirp[n] = e^{+i pi n^2/NL}, kc[i] = e^{-i pi d^2/NL}
// wrapped to M (linear-conv kernel), exact int64 phase reduction mod 2*NL.
// ---------------------------------------------------------------------------
__global__ void k_setup(float2* __restrict__ kc, float2* __restrict__ bchirp, int NL) {
    int t = blockIdx.x * blockDim.x + threadIdx.x;
    long long twoNL = 2LL * NL;
    if (t < M_FFT) {
        long long d = 0; bool act = false;
        if (t < NL)              { d = t;        act = true; }
        else if (t > M_FFT - NL) { d = t - M_FFT; act = true; }
        float2 v = make_float2(0.f, 0.f);
        if (act) {
            long long ph = (d * d) % twoNL;
            float th = -PI_F * (float)ph / (float)NL;
            float s, c; sincosf(th, &s, &c);
            v = make_float2(c, s);
        }
        kc[t] = v;
    } else {
        int n = t - M_FFT;
        if (n < NL) {
            long long ph = ((long long)n * n) % twoNL;
            float th = PI_F * (float)ph / (float)NL;
            float s, c; sincosf(th, &s, &c);
            bchirp[n] = make_float2(c, s);
        }
    }
}

// ---------------------------------------------------------------------------
// In-LDS radix-2 FFT-128 helpers. 16 FFTs per 256-thread block, 16 thr/FFT.
// DIF: natural in -> bitrev out, W = e^{-2pi i k/128}.
// DIT: bitrev in -> natural out, conj twiddles (unnormalized inverse).
// ---------------------------------------------------------------------------
__device__ void fft128_dif(float2 (*ld)[129], const float2* tw, int f, int q) {
    for (int ls = 6; ls >= 0; --ls) {
        int span = 1 << ls;
        for (int b = q; b < 64; b += 16) {
            int j = b & (span - 1);
            int g = b >> ls;
            int u = (g << (ls + 1)) + j;
            int v = u + span;
            float2 A = ld[f][u], B = ld[f][v];
            float2 s = make_float2(A.x + B.x, A.y + B.y);
            float2 d = make_float2(A.x - B.x, A.y - B.y);
            ld[f][u] = s;
            ld[f][v] = cmul(d, tw[j << (6 - ls)]);
        }
        __syncthreads();
    }
}

__device__ void fft128_dit(float2 (*ld)[129], const float2* tw, int f, int q) {
    for (int ls = 0; ls <= 6; ++ls) {
        int span = 1 << ls;
        for (int b = q; b < 64; b += 16) {
            int j = b & (span - 1);
            int g = b >> ls;
            int u = (g << (ls + 1)) + j;
            int v = u + span;
            float2 w = tw[j << (6 - ls)];
            w.y = -w.y;                       // conj -> e^{+...}
            float2 A = ld[f][u];
            float2 t = cmul(ld[f][v], w);
            ld[f][u] = make_float2(A.x + t.x, A.y + t.y);
            ld[f][v] = make_float2(A.x - t.x, A.y - t.y);
        }
        __syncthreads();
    }
}

#define FFT_PROLOG                                                        \
    __shared__ float2 ld[16][129];                                        \
    __shared__ float2 tw[64];                                             \
    if (threadIdx.x < 64) {                                               \
        float th = -TWO_PI_F * (float)threadIdx.x / 128.0f;               \
        float s, c; sincosf(th, &s, &c);                                  \
        tw[threadIdx.x] = make_float2(c, s);                              \
    }

// Forward step 1: column FFTs (over r, stride 128) + twiddle W_M^{-c*k1}.
__global__ __launch_bounds__(TPB) void kfft_cols_fwd(float2* __restrict__ P) {
    const int cg = blockIdx.x;                    // [0,8)
    const size_t vb = (size_t)blockIdx.y * M_FFT;
    FFT_PROLOG
    const int c0 = cg * 16;
    for (int i = threadIdx.x; i < 2048; i += TPB) {
        int cl = i & 15, r = i >> 4;
        ld[cl][r] = P[vb + (c0 + cl) + 128 * r];
    }
    __syncthreads();
    fft128_dif(ld, tw, threadIdx.x >> 4, threadIdx.x & 15);
    for (int i = threadIdx.x; i < 2048; i += TPB) {
        int cl = i & 15, pos = i >> 4;
        int c = c0 + cl;
        int k1 = rev7(pos);
        float th = -TWO_PI_F * (float)(c * k1) / (float)M_FFT;
        float s, co; sincosf(th, &s, &co);
        P[vb + c + 128 * pos] = cmul(ld[cl][pos], make_float2(co, s));
    }
}

// Forward step 2: row FFTs (contiguous), no twiddle.
__global__ __launch_bounds__(TPB) void kfft_rows_fwd(float2* __restrict__ P) {
    const int rg = blockIdx.x;
    const size_t vb = (size_t)blockIdx.y * M_FFT;
    FFT_PROLOG
    const int R0 = rg * 16;
    for (int i = threadIdx.x; i < 2048; i += TPB) {
        int fl = i >> 7, c = i & 127;
        ld[fl][c] = P[vb + (size_t)(R0 + fl) * 128 + c];
    }
    __syncthreads();
    fft128_dif(ld, tw, threadIdx.x >> 4, threadIdx.x & 15);
    for (int i = threadIdx.x; i < 2048; i += TPB) {
        int fl = i >> 7, pos = i & 127;
        P[vb + (size_t)(R0 + fl) * 128 + pos] = ld[fl][pos];
    }
}

// Inverse step 1: row DIT FFTs; multiply KF at load; twiddle W_M^{+rev7(R)*pos}
// after. (Input rows are sigma(k1), elements at sigma(k2) -> DIT bitrev-in.)
__global__ __launch_bounds__(TPB) void kfft_rows_inv(float2* __restrict__ P,
                                                     const float2* __restrict__ KF) {
    const int rg = blockIdx.x;
    const size_t vb = (size_t)blockIdx.y * M_FFT;
    FFT_PROLOG
    const int R0 = rg * 16;
    for (int i = threadIdx.x; i < 2048; i += TPB) {
        int fl = i >> 7, c = i & 127;
        size_t p = (size_t)(R0 + fl) * 128 + c;
        ld[fl][c] = cmul(P[vb + p], KF[p]);
    }
    __syncthreads();
    fft128_dit(ld, tw, threadIdx.x >> 4, threadIdx.x & 15);
    for (int i = threadIdx.x; i < 2048; i += TPB) {
        int fl = i >> 7, pos = i & 127;
        int R = R0 + fl;
        int k1 = rev7(R);
        float th = TWO_PI_F * (float)(k1 * pos) / (float)M_FFT;
        float s, co; sincosf(th, &s, &co);
        P[vb + (size_t)R * 128 + pos] = cmul(ld[fl][pos], make_float2(co, s));
    }
}

// Inverse step 2: column DIT FFTs (rows are sigma(k1) -> bitrev-in), output
// natural: y[n1+128*n2] lands at p = n1+128*n2. No twiddle.
__global__ __launch_bounds__(TPB) void kfft_cols_inv(float2* __restrict__ P) {
    const int cg = blockIdx.x;
    const size_t vb = (size_t)blockIdx.y * M_FFT;
    FFT_PROLOG
    const int c0 = cg * 16;
    for (int i = threadIdx.x; i < 2048; i += TPB) {
        int cl = i & 15, r = i >> 4;
        ld[cl][r] = P[vb + (c0 + cl) + 128 * r];
    }
    __syncthreads();
    fft128_dit(ld, tw, threadIdx.x >> 4, threadIdx.x & 15);
    for (int i = threadIdx.x; i < 2048; i += TPB) {
        int cl = i & 15, pos = i >> 4;
        P[vb + (c0 + cl) + 128 * pos] = ld[cl][pos];
    }
}

// ---------------------------------------------------------------------------
// K_GATHER: build a[m] = c[m]*bchirp[m] zero-padded to M for each transform.
// c[m] = G[j,m] * ft[r, idx[j,m]], nonzero only in head [0,h) / tail blocks.
// ---------------------------------------------------------------------------
__global__ __launch_bounds__(TPB) void k_gather(const float* __restrict__ Gm,
        const int* __restrict__ idxp, const float2* __restrict__ A,
        const int* __restrict__ hnh, const float2* __restrict__ bchirp,
        float2* __restrict__ P, int NB, int NL, int vbase) {
    const int vg = vbase + blockIdx.x;
    const int r = vg / NB, j = vg % NB;
    const int h = hnh[2 * j], nh = hnh[2 * j + 1];
    const float* Gj = Gm + (size_t)j * NL;
    const int*   ij = idxp + (size_t)j * NL;
    const float2* Ar = A + (size_t)r * LS;
    float2* Pv = P + (size_t)blockIdx.x * M_FFT;
    const int tail0 = NL - nh;
    for (int i = threadIdx.x; i < M_FFT; i += TPB) {
        float2 val = make_float2(0.f, 0.f);
        if (i < h || (i >= tail0 && i < NL)) {
            int k = ij[i];
            int k1 = k % N1, k2 = k / N1;
            float2 f = Ar[(size_t)k1 * N2 + k2];
            float  g = Gj[i];
            val = cmul(make_float2(f.x * g, f.y * g), bchirp[i]);
        }
        Pv[i] = val;
    }
}

// ---------------------------------------------------------------------------
// K_FIN: out[n] = P[n] * bchirp[n] * 100/(NL*M)  (natural order, coalesced).
// ---------------------------------------------------------------------------
__global__ __launch_bounds__(TPB) void k_fin(const float2* __restrict__ P,
        const float2* __restrict__ bchirp, float2* __restrict__ out,
        int NL, int vbase) {
    const int vloc = blockIdx.y;
    const float2* Pv = P + (size_t)vloc * M_FFT;
    float2* outv = out + (size_t)(vbase + vloc) * NL;
    const float sc = 100.0f / ((float)NL * (float)M_FFT);
    for (int n = blockIdx.x * TPB + threadIdx.x; n < NL; n += gridDim.x * TPB) {
        float2 y = cmul(Pv[n], bchirp[n]);
        outv[n] = make_float2(y.x * sc, y.y * sc);
    }
}

// ---------------------------------------------------------------------------
// Legacy direct zoom-IDFT (round-1 proven) — fallback if ws too small.
// ---------------------------------------------------------------------------
__global__ __launch_bounds__(TPB) void k3_idft(const float* __restrict__ G,
                                               const int*  __restrict__ idxp,
                                               const float2* __restrict__ FT,
                                               const int*  __restrict__ hnh,
                                               float2* __restrict__ out,
                                               int NB, int NL) {
    extern __shared__ float2 cls[];
    const int j = blockIdx.x;
    const int r = blockIdx.y;
    const int h  = hnh[2 * j];
    const int nh = hnh[2 * j + 1];
    const int Lg = h + nh;
    const float* Gj = G    + (size_t)j * NL;
    const int*   ij = idxp + (size_t)j * NL;

    for (int t = threadIdx.x; t < Lg; t += TPB) {
        int m = (t < h) ? t : (NL - nh + (t - h));
        int k = ij[m];
        float2 f = FT[((size_t)r * N1 + (k % N1)) * N2 + (k / N1)];
        float  g = Gj[m];
        cls[t] = make_float2(f.x * g, f.y * g);
    }
    __syncthreads();

    const float scale = 100.0f / (float)NL;
    const float w0 = TWO_PI_F / (float)NL;
    float2* outr = out + ((size_t)r * NB + j) * NL;

    for (int n_base = 0; n_base < NL; n_base += 4 * TPB) {
        int   n[4];
        float are[4], aim[4], twr[4], twi[4], str[4], sti[4];
        #pragma unroll
        for (int u = 0; u < 4; ++u) {
            n[u] = n_base + u * TPB + (int)threadIdx.x;
            are[u] = 0.f; aim[u] = 0.f;
            float s, c; sincosf(w0 * (float)(n[u] % NL), &s, &c);
            str[u] = c; sti[u] = s;
            twr[u] = 1.f; twi[u] = 0.f;
        }
        for (int t = 0; t < h; ++t) {
            if ((t & 255) == 0) {
                #pragma unroll
                for (int u = 0; u < 4; ++u) {
                    int mm = (int)(((long long)t * (long long)n[u]) % NL);
                    float s, c; sincosf(w0 * (float)mm, &s, &c);
                    twr[u] = c; twi[u] = s;
                }
            }
            float2 cv = cls[t];
            #pragma unroll
            for (int u = 0; u < 4; ++u) {
                are[u] = fmaf(cv.x, twr[u], are[u]);
                are[u] = fmaf(-cv.y, twi[u], are[u]);
                aim[u] = fmaf(cv.x, twi[u], aim[u]);
                aim[u] = fmaf(cv.y, twr[u], aim[u]);
                float nr = twr[u] * str[u] - twi[u] * sti[u];
                float ni = twr[u] * sti[u] + twi[u] * str[u];
                twr[u] = nr; twi[u] = ni;
            }
        }
        const int m0 = NL - nh;
        for (int t = 0; t < nh; ++t) {
            if ((t & 255) == 0) {
                #pragma unroll
                for (int u = 0; u < 4; ++u) {
                    int mm = (int)(((long long)(m0 + t) * (long long)n[u]) % NL);
                    float s, c; sincosf(w0 * (float)mm, &s, &c);
                    twr[u] = c; twi[u] = s;
                }
            }
            float2 cv = cls[h + t];
            #pragma unroll
            for (int u = 0; u < 4; ++u) {
                are[u] = fmaf(cv.x, twr[u], are[u]);
                are[u] = fmaf(-cv.y, twi[u], are[u]);
                aim[u] = fmaf(cv.x, twi[u], aim[u]);
                aim[u] = fmaf(cv.y, twr[u], aim[u]);
                float nr = twr[u] * str[u] - twi[u] * sti[u];
                float ni = twr[u] * sti[u] + twi[u] * str[u];
                twr[u] = nr; twi[u] = ni;
            }
        }
        #pragma unroll
        for (int u = 0; u < 4; ++u) {
            if (n[u] < NL) outr[n[u]] = make_float2(are[u] * scale, aim[u] * scale);
        }
    }
}

// ---------------------------------------------------------------------------
static inline size_t align256(size_t x) { return (x + 255) & ~(size_t)255; }

extern "C" void kernel_launch(void* const* d_in, const int* in_sizes, int n_in,
                              void* d_out, int out_size, void* d_ws, size_t ws_size,
                              hipStream_t stream) {
    const float* x   = (const float*)d_in[0];
    const float* Gm  = (const float*)d_in[1];
    const int*   idx = (const int*)d_in[2];
    float2*      out = (float2*)d_out;

    const int p  = in_sizes[1];
    const int NB = (p % 114 == 0) ? 114 : 115;
    const int NL = p / NB;
    const int B  = NB * ROWS;

    // ws layout
    size_t hnh_off    = 0;
    size_t bchirp_off = align256(hnh_off + 2048);
    size_t kc_off     = align256(bchirp_off + (size_t)NL * 8);
    size_t A_off      = align256(kc_off + (size_t)M_FFT * 8);
    size_t P_off      = align256(A_off + (size_t)ROWS * LS * 8);

    int*    hnh    = (int*)((char*)d_ws + hnh_off);
    float2* bchirp = (float2*)((char*)d_ws + bchirp_off);
    float2* kc     = (float2*)((char*)d_ws + kc_off);
    float2* A      = (float2*)((char*)d_ws + A_off);
    float2* P      = (float2*)((char*)d_ws + P_off);

    // pick chunk count (fewest chunks whose P fits); 0 => legacy fallback
    int nc = 0, nTc = 0;
    if (2 * NL - 1 <= M_FFT) {
        const int cand[] = {1, 2, 3, 4, 6, 8, 12, 16, 24, 32, 48, 64};
        for (int t : cand) {
            int ch = (B + t - 1) / t;
            if (P_off + (size_t)ch * M_FFT * 8 <= ws_size) { nc = t; nTc = ch; break; }
        }
    }

    k0_scan<<<dim3(NB), TPB, 0, stream>>>(Gm, NL, hnh);
    k1_dft525<<<dim3(N2, ROWS), TPB, 0, stream>>>(x, A);
    k2_dft504<<<dim3(N1, ROWS), TPB, 0, stream>>>(A);

    if (nc > 0) {
        int setup_blocks = (M_FFT + NL + TPB - 1) / TPB;
        k_setup<<<dim3(setup_blocks), TPB, 0, stream>>>(kc, bchirp, NL);
        // KF = fwd-FFT(kc) in the pipeline's stored layout
        kfft_cols_fwd<<<dim3(8, 1), TPB, 0, stream>>>(kc);
        kfft_rows_fwd<<<dim3(8, 1), TPB, 0, stream>>>(kc);

        for (int c = 0; c < nc; ++c) {
            int vbase = c * nTc;
            if (vbase >= B) break;
            int n = B - vbase < nTc ? B - vbase : nTc;
            k_gather<<<dim3(n), TPB, 0, stream>>>(Gm, idx, A, hnh, bchirp, P, NB, NL, vbase);
            kfft_cols_fwd<<<dim3(8, n), TPB, 0, stream>>>(P);
            kfft_rows_fwd<<<dim3(8, n), TPB, 0, stream>>>(P);
            kfft_rows_inv<<<dim3(8, n), TPB, 0, stream>>>(P, kc);
            kfft_cols_inv<<<dim3(8, n), TPB, 0, stream>>>(P);
            k_fin<<<dim3(32, n), TPB, 0, stream>>>(P, bchirp, out, NL, vbase);
        }
    } else {
        k3_idft<<<dim3(NB, ROWS), TPB, (size_t)NL * sizeof(float2), stream>>>(
            Gm, idx, A, hnh, out, NB, NL);
    }
}